// Round 13
// baseline (153.118 us; speedup 1.0000x reference)
//
#include <hip/hip_runtime.h>
#include <hip/hip_bf16.h>
#include <hip/hip_fp16.h>

#define Hh 128
#define Ww 160
#define Cc 32
#define Dd 48
#define Bb 2
#define Vv 3
#define HW (Hh*Ww)
#define VS 32    // vsh channel stride in f16 units: no pad; XOR swizzle keeps banks spread

typedef _Float16 f16x8 __attribute__((ext_vector_type(8)));
typedef float f32x4 __attribute__((ext_vector_type(4)));

// ---------------- K1: transpose (v,b,c,h,w) fp32 -> (v,b,h,w,c) fp16 --------
// Block 0 additionally computes proj matrices (threads 0..3) and the f16 MFMA
// B-fragment table Bfr[tap][lane] (threads 0..63): w[kd=lane&15][c=q*8+j][tap].
__global__ void k_transpose(const float* __restrict__ f, const float* __restrict__ pm,
                            const float* __restrict__ wt, ushort* __restrict__ featT,
                            float* __restrict__ P, ushort* __restrict__ Bfr) {
    __shared__ float t[Cc][Ww + 1];
    const int tid = threadIdx.x;
    if (blockIdx.x == 0 && tid < 64) {
        if (tid < Bb * (Vv - 1)) {
            int b = tid >> 1;
            int v = (tid & 1) + 1;
            const float* ref = pm + (b * Vv + 0) * 16;
            const float* src = pm + (b * Vv + v) * 16;
            float A[4][8];
            for (int i = 0; i < 4; ++i)
                for (int j = 0; j < 4; ++j) {
                    A[i][j] = ref[i * 4 + j];
                    A[i][4 + j] = (i == j) ? 1.0f : 0.0f;
                }
            for (int col = 0; col < 4; ++col) {
                int piv = col;
                for (int r = col + 1; r < 4; ++r)
                    if (fabsf(A[r][col]) > fabsf(A[piv][col])) piv = r;
                if (piv != col)
                    for (int j = 0; j < 8; ++j) { float tmp = A[col][j]; A[col][j] = A[piv][j]; A[piv][j] = tmp; }
                float inv = 1.0f / A[col][col];
                for (int j = 0; j < 8; ++j) A[col][j] *= inv;
                for (int r = 0; r < 4; ++r) {
                    if (r == col) continue;
                    float fct = A[r][col];
                    for (int j = 0; j < 8; ++j) A[r][j] -= fct * A[col][j];
                }
            }
            float Pm[3][4];
            for (int i = 0; i < 3; ++i)
                for (int j = 0; j < 4; ++j) {
                    float s = 0.f;
                    for (int k = 0; k < 4; ++k) s += src[i * 4 + k] * A[k][4 + j];
                    Pm[i][j] = s;
                }
            float* o = P + tid * 12;
            o[0] = Pm[0][0]; o[1] = Pm[0][1]; o[2] = Pm[0][2];
            o[3] = Pm[1][0]; o[4] = Pm[1][1]; o[5] = Pm[1][2];
            o[6] = Pm[2][0]; o[7] = Pm[2][1]; o[8] = Pm[2][2];
            o[9] = Pm[0][3]; o[10] = Pm[1][3]; o[11] = Pm[2][3];
        }
        int kd = tid & 15, q = tid >> 4;
        for (int tap = 0; tap < 9; ++tap) {
            ushort* dst = Bfr + (tap * 64 + tid) * 8;
            for (int j = 0; j < 8; ++j) {
                float w = (kd < 3) ? wt[(q * 8 + j) * 27 + kd * 9 + tap] : 0.f;
                __half h = __float2half(w);
                dst[j] = *(ushort*)&h;
            }
        }
    }
    int slice = blockIdx.x;          // vb*H + y
    int vb = slice / Hh, y = slice % Hh;
    const float* src = f + (size_t)vb * Cc * HW + (size_t)y * Ww;
    ushort* dst = featT + ((size_t)vb * Hh + y) * Ww * Cc;
    for (int i = tid; i < Cc * (Ww / 4); i += 256) {
        int c = i / (Ww / 4), x4 = (i - c * (Ww / 4)) * 4;
        float4 v = *(const float4*)(src + (size_t)c * HW + x4);
        t[c][x4] = v.x; t[c][x4 + 1] = v.y; t[c][x4 + 2] = v.z; t[c][x4 + 3] = v.w;
    }
    __syncthreads();
    for (int i = tid; i < Ww * 4; i += 256) {
        int x = i >> 2, c8 = i & 3;
        union { uint4 u; ushort s[8]; } pk;
#pragma unroll
        for (int j = 0; j < 8; ++j) {
            __half h = __float2half(t[c8 * 8 + j][x]);
            pk.s[j] = *(ushort*)&h;
        }
        *(uint4*)&dst[x * Cc + c8 * 8] = pk.u;
    }
}

// ---------------- K2: f16 variance tile + f16 MFMA 3x3 conv -> S (f16) ------
// R13: XCD-aware grid swizzle. Old (tile-fast, d, b) order put ~2 full d-rows
// (all 80 tiles, ~5 MB footprint) resident per XCD -> per-XCD 4 MB L2
// thrashed and gathers fell to L3 — the 77 us floor that occupancy (R9),
// instruction count (R10/R11), and L1-transaction layout (R8 vs R11) all
// failed to move. New decode: xcd=bx&7 round-robin; each XCD runs one tile
// for 6 consecutive depths (band d = xcd*6 + g%6) -> resident footprint
// ~1.6 MB/XCD, gathers become L2 hits.
__global__ __launch_bounds__(256, 5)
void k_main(const ushort* __restrict__ featT, const float* __restrict__ P,
            const float* __restrict__ dvals, const ushort* __restrict__ Bfr,
            ushort* __restrict__ S) {
    __shared__ ushort vsh[324 * VS];          // 20.7 KB f16 variance tile (32 ch)
    __shared__ unsigned int offs[324 * 4];    // 5.2 KB packed corner pixel idx
    __shared__ unsigned int wgts[324 * 4];    // 5.2 KB packed fp16 weights
    __shared__ float rt[24];
    const int tid = threadIdx.x;
    const int bx = blockIdx.x;
    const int xcd = bx & 7;
    const int g = bx >> 3;                    // 0..479
    const int tile = g / 6;                   // 0..79
    const int d = xcd * 6 + (g - tile * 6);   // 0..47
    const int b = blockIdx.y;
    const int tileY = tile / 10, tileX = tile - (tile / 10) * 10;

    if (tid < 24) rt[tid] = P[b * 24 + tid];
    const float depth = dvals[b * Dd + d];
    __syncthreads();

    // ---- stage A: bilinear coords for all 324 slots, once per block ----
#pragma unroll 1
    for (int p = tid; p < 324; p += 256) {
        int pyt = p / 18, pxt = p - pyt * 18;
        int gy = tileY * 16 + pyt - 1, gx = tileX * 16 + pxt - 1;
        if ((unsigned)gy >= (unsigned)Hh || (unsigned)gx >= (unsigned)Ww) continue;
#pragma unroll
        for (int vi = 0; vi < 2; ++vi) {
            const float* M = &rt[vi * 12];
            float fgx = (float)gx, fgy = (float)gy;
            float rx = M[0] * fgx + M[1] * fgy + M[2];
            float ry = M[3] * fgx + M[4] * fgy + M[5];
            float rz = M[6] * fgx + M[7] * fgy + M[8];
            float X = rx * depth + M[9];
            float Y = ry * depth + M[10];
            float Z = rz * depth + M[11];
            float z = (fabsf(Z) < 1e-6f) ? 1e-6f : Z;
            float u = X / z, vv = Y / z;
            float x0f = floorf(u), y0f = floorf(vv);
            float fx = u - x0f, fy = vv - y0f;
            int x0 = (int)x0f, y0 = (int)y0f;
            int x1 = x0 + 1, y1 = y0 + 1;
            bool vx0 = (x0 >= 0) && (x0 <= Ww - 1);
            bool vx1 = (x1 >= 0) && (x1 <= Ww - 1);
            bool vy0 = (y0 >= 0) && (y0 <= Hh - 1);
            bool vy1 = (y1 >= 0) && (y1 <= Hh - 1);
            int xc0 = min(max(x0, 0), Ww - 1), xc1 = min(max(x1, 0), Ww - 1);
            int yc0 = min(max(y0, 0), Hh - 1), yc1 = min(max(y1, 0), Hh - 1);
            unsigned int p00 = (unsigned)(yc0 * Ww + xc0);
            unsigned int p01 = (unsigned)(yc0 * Ww + xc1);
            unsigned int p10 = (unsigned)(yc1 * Ww + xc0);
            unsigned int p11 = (unsigned)(yc1 * Ww + xc1);
            float w0 = (vx0 && vy0) ? (1.f - fx) * (1.f - fy) : 0.f;
            float w1 = (vx1 && vy0) ? fx * (1.f - fy) : 0.f;
            float w2 = (vx0 && vy1) ? (1.f - fx) * fy : 0.f;
            float w3 = (vx1 && vy1) ? fx * fy : 0.f;
            offs[p * 4 + vi * 2 + 0] = p00 | (p01 << 16);
            offs[p * 4 + vi * 2 + 1] = p10 | (p11 << 16);
            __half2 ha = __floats2half2_rn(w0, w1);
            __half2 hb = __floats2half2_rn(w2, w3);
            wgts[p * 4 + vi * 2 + 0] = *(unsigned int*)&ha;
            wgts[p * 4 + vi * 2 + 1] = *(unsigned int*)&hb;
        }
    }
    __syncthreads();

    const ushort* b1 = featT + (size_t)(1 * Bb + b) * HW * Cc;
    const ushort* b2 = featT + (size_t)(2 * Bb + b) * HW * Cc;
    const ushort* br = featT + (size_t)b * HW * Cc;

    // ---- stage B: gather items (slot, c16 0..1): 648 items, f16 math ----
#pragma unroll 1
    for (int i = tid; i < 648; i += 256) {
        int p = i >> 1, half16 = i & 1;
        int c16 = half16 << 4;                 // channel offset 0 or 16
        int pyt = p / 18, pxt = p - pyt * 18;
        int gy = tileY * 16 + pyt - 1, gx = tileX * 16 + pxt - 1;
        int sw0 = ((half16 * 2 + 0) ^ (p & 3)) * 8;
        int sw1 = ((half16 * 2 + 1) ^ (p & 3)) * 8;
        ushort* dst0 = &vsh[p * VS + sw0];
        ushort* dst1 = &vsh[p * VS + sw1];
        if ((unsigned)gy >= (unsigned)Hh || (unsigned)gx >= (unsigned)Ww) {
            *(uint4*)dst0 = make_uint4(0u, 0u, 0u, 0u);
            *(uint4*)dst1 = make_uint4(0u, 0u, 0u, 0u);
            continue;
        }
        uint4 oo = *(const uint4*)&offs[p * 4];
        uint4 wwp = *(const uint4*)&wgts[p * 4];
        int o00 = (int)(oo.x & 0xffffu) * Cc + c16;
        int o01 = (int)(oo.x >> 16)     * Cc + c16;
        int o10 = (int)(oo.y & 0xffffu) * Cc + c16;
        int o11 = (int)(oo.y >> 16)     * Cc + c16;
        int o20 = (int)(oo.z & 0xffffu) * Cc + c16;
        int o21 = (int)(oo.z >> 16)     * Cc + c16;
        int o30 = (int)(oo.w & 0xffffu) * Cc + c16;
        int o31 = (int)(oo.w >> 16)     * Cc + c16;
        int orf = (gy * Ww + gx) * Cc + c16;
        __half2 hv0 = *(__half2*)&wwp.x;   // v0: (w0,w1)
        __half2 hv1 = *(__half2*)&wwp.y;   // v0: (w2,w3)
        __half2 hv2 = *(__half2*)&wwp.z;   // v1: (w0,w1)
        __half2 hv3 = *(__half2*)&wwp.w;   // v1: (w2,w3)
        __half2 w00 = __half2half2(__low2half(hv0)), w01 = __half2half2(__high2half(hv0));
        __half2 w02 = __half2half2(__low2half(hv1)), w03 = __half2half2(__high2half(hv1));
        __half2 w10 = __half2half2(__low2half(hv2)), w11 = __half2half2(__high2half(hv2));
        __half2 w12 = __half2half2(__low2half(hv3)), w13 = __half2half2(__high2half(hv3));
        const __half2 third2 = __float2half2_rn(1.0f / 3.0f);
        union U { uint4 u; __half2 h[4]; };
#pragma unroll
        for (int h = 0; h < 2; ++h) {
            int e = h * 8;
            U R, C0, C1, C2, C3, E0, E1, E2, E3, V;
            R.u  = *(const uint4*)(br + orf + e);
            C0.u = *(const uint4*)(b1 + o00 + e);
            C1.u = *(const uint4*)(b1 + o01 + e);
            C2.u = *(const uint4*)(b1 + o10 + e);
            C3.u = *(const uint4*)(b1 + o11 + e);
            E0.u = *(const uint4*)(b2 + o20 + e);
            E1.u = *(const uint4*)(b2 + o21 + e);
            E2.u = *(const uint4*)(b2 + o30 + e);
            E3.u = *(const uint4*)(b2 + o31 + e);
#pragma unroll
            for (int k = 0; k < 4; ++k) {
                __half2 s1 = __hmul2(w00, C0.h[k]);
                s1 = __hfma2(w01, C1.h[k], s1);
                s1 = __hfma2(w02, C2.h[k], s1);
                s1 = __hfma2(w03, C3.h[k], s1);
                __half2 s2 = __hmul2(w10, E0.h[k]);
                s2 = __hfma2(w11, E1.h[k], s2);
                s2 = __hfma2(w12, E2.h[k], s2);
                s2 = __hfma2(w13, E3.h[k], s2);
                __half2 r = R.h[k];
                __half2 sum = __hadd2(__hadd2(r, s1), s2);
                __half2 sq = __hmul2(r, r);
                sq = __hfma2(s1, s1, sq);
                sq = __hfma2(s2, s2, sq);
                __half2 m = __hmul2(sum, third2);
                __half2 var = __hfma2(__hneg2(m), m, __hmul2(sq, third2));
                V.h[k] = var;
            }
            *(uint4*)(h ? dst1 : dst0) = V.u;
        }
    }
    __syncthreads();

    // ---- phase 2: f16 MFMA conv. Wave covers 4 row-groups of 16 pixels. ----
    const int lane = tid & 63;
    const int wave = tid >> 6;
    const int q = lane >> 4;      // k-chunk selector (channels q*8..+7) / D row quad
    const int n = lane & 15;      // A: pixel-x ; B/D: kd column
    uint4 bf[9];
#pragma unroll
    for (int tap = 0; tap < 9; ++tap)
        bf[tap] = *(const uint4*)(Bfr + ((tap * 64 + lane) << 3));
#pragma unroll 1
    for (int rr = 0; rr < 4; ++rr) {
        int row = wave * 4 + rr;            // ty of this 16-pixel row-group
        f32x4 acc = {0.f, 0.f, 0.f, 0.f};
#pragma unroll
        for (int tap = 0; tap < 9; ++tap) {
            int kh = tap / 3, kw = tap - 3 * (tap / 3);
            int slot = (row + kh) * 18 + n + kw;
            union { uint4 u; f16x8 v; } A, Bf;
            A.u  = *(const uint4*)&vsh[slot * VS + (q ^ (slot & 3)) * 8];
            Bf.u = bf[tap];
            acc = __builtin_amdgcn_mfma_f32_16x16x32_f16(A.v, Bf.v, acc, 0, 0, 0);
        }
        if (n < 3) {   // lane holds D[pixel-x = q*4+reg][kd = n]; store 4 px as f16
            int gy = tileY * 16 + row;
            int gxb = tileX * 16 + q * 4;
            union { uint2 u; ushort s[4]; } pk;
#pragma unroll
            for (int j = 0; j < 4; ++j) {
                __half h = __float2half(acc[j]);
                pk.s[j] = *(ushort*)&h;
            }
            *(uint2*)&S[((size_t)(b * 3 + n) * Dd + d) * HW + (size_t)gy * Ww + gxb] = pk.u;
        }
    }
}

// ---------------- K3: cost, softmax, depth + conf; 2 px/thread, 4-way d ----
__global__ __launch_bounds__(256)
void k_post(const ushort* __restrict__ S, const float* __restrict__ dvals,
            float* __restrict__ out) {
    const int tid = threadIdx.x;
    const int lane = tid & 63, wave = tid >> 6;
    const int q = lane >> 4;                        // d-chunk: d = q*12 + j
    const int pl = lane & 15;                       // pixel-pair within group
    int gid = ((blockIdx.x * 4 + wave) * 16 + pl) * 2;   // global pixel (even)
    int b = gid / HW;
    int pix = gid - b * HW;
    const ushort* S0 = S + ((size_t)(b * 3 + 0) * Dd) * HW + pix;
    const ushort* S1 = S + ((size_t)(b * 3 + 1) * Dd) * HW + pix;
    const ushort* S2 = S + ((size_t)(b * 3 + 2) * Dd) * HW + pix;
    const int d0 = q * 12;
    float2 cost[12];
#pragma unroll
    for (int j = 0; j < 12; ++j) {
        int dd = d0 + j;
        float2 c = __half22float2(*(const __half2*)&S1[(size_t)dd * HW]);
        if (dd > 0) {
            float2 a = __half22float2(*(const __half2*)&S0[(size_t)(dd - 1) * HW]);
            c.x += a.x; c.y += a.y;
        }
        if (dd < Dd - 1) {
            float2 a = __half22float2(*(const __half2*)&S2[(size_t)(dd + 1) * HW]);
            c.x += a.x; c.y += a.y;
        }
        cost[j] = c;
    }
    float mx = cost[0].x, my = cost[0].y;
#pragma unroll
    for (int j = 1; j < 12; ++j) { mx = fmaxf(mx, cost[j].x); my = fmaxf(my, cost[j].y); }
    mx = fmaxf(mx, __shfl_xor(mx, 16)); mx = fmaxf(mx, __shfl_xor(mx, 32));
    my = fmaxf(my, __shfl_xor(my, 16)); my = fmaxf(my, __shfl_xor(my, 32));
    float sx = 0.f, sy = 0.f, depx = 0.f, depy = 0.f, dix = 0.f, diy = 0.f;
#pragma unroll
    for (int j = 0; j < 12; ++j) {
        float dv = dvals[b * Dd + d0 + j];
        float fd = (float)(d0 + j);
        float ex = __expf(cost[j].x - mx);
        float ey = __expf(cost[j].y - my);
        cost[j].x = ex; cost[j].y = ey;
        sx += ex; sy += ey;
        depx += ex * dv; depy += ey * dv;
        dix += ex * fd;  diy += ey * fd;
    }
    sx += __shfl_xor(sx, 16); sx += __shfl_xor(sx, 32);
    sy += __shfl_xor(sy, 16); sy += __shfl_xor(sy, 32);
    depx += __shfl_xor(depx, 16); depx += __shfl_xor(depx, 32);
    depy += __shfl_xor(depy, 16); depy += __shfl_xor(depy, 32);
    dix += __shfl_xor(dix, 16); dix += __shfl_xor(dix, 32);
    diy += __shfl_xor(diy, 16); diy += __shfl_xor(diy, 32);
    float invx = 1.0f / sx, invy = 1.0f / sy;
    int didx = min(max((int)(dix * invx), 0), Dd - 1);
    int didy = min(max((int)(diy * invy), 0), Dd - 1);
    float wx = 0.f, wy = 0.f;
#pragma unroll
    for (int j = 0; j < 12; ++j) {
        int dd = d0 + j;
        wx += ((dd >= didx - 1) && (dd <= didx + 2)) ? cost[j].x : 0.f;
        wy += ((dd >= didy - 1) && (dd <= didy + 2)) ? cost[j].y : 0.f;
    }
    wx += __shfl_xor(wx, 16); wx += __shfl_xor(wx, 32);
    wy += __shfl_xor(wy, 16); wy += __shfl_xor(wy, 32);
    if (q == 0) {
        *(float2*)&out[gid] = make_float2(depx * invx, depy * invy);
        *(float2*)&out[Bb * HW + gid] = make_float2(wx * invx, wy * invy);
    }
}

// ---------------- launch ----------------------------------------------------
extern "C" void kernel_launch(void* const* d_in, const int* in_sizes, int n_in,
                              void* d_out, int out_size, void* d_ws, size_t ws_size,
                              hipStream_t stream) {
    const float* features = (const float*)d_in[0];   // (V,B,C,H,W)
    const float* pm       = (const float*)d_in[1];   // (B,V,4,4)
    const float* dvals    = (const float*)d_in[2];   // (B,D)
    const float* reg_w    = (const float*)d_in[4];   // (1,C,3,3,3)
    float* outp = (float*)d_out;

    char* ws = (char*)d_ws;
    ushort* featT = (ushort*)ws;                                 // V*B*H*W*C f16
    size_t featT_bytes = (size_t)Vv * Bb * Hh * Ww * Cc * sizeof(ushort);
    float* P = (float*)(ws + featT_bytes);                       // 48 floats
    ushort* S = (ushort*)(ws + featT_bytes + 512);               // B*3*D*H*W f16
    size_t S_bytes = (size_t)Bb * 3 * Dd * HW * sizeof(ushort);
    ushort* Bfr = (ushort*)(ws + featT_bytes + 512 + S_bytes);   // 9*64*8 f16

    k_transpose<<<Vv * Bb * Hh, 256, 0, stream>>>(features, pm, reg_w, featT, P, Bfr);
    k_main<<<dim3(80 * Dd, Bb), 256, 0, stream>>>(featT, P, dvals, Bfr, S);
    k_post<<<(Bb * HW) / 128, 256, 0, stream>>>(S, dvals, outp);
}

// Round 14
// 149.989 us; speedup vs baseline: 1.0209x; 1.0209x over previous
//
#include <hip/hip_runtime.h>
#include <hip/hip_bf16.h>
#include <hip/hip_fp16.h>

#define Hh 128
#define Ww 160
#define Cc 32
#define Dd 48
#define Bb 2
#define Vv 3
#define HW (Hh*Ww)
#define VS 32    // vsh channel stride in f16 units: no pad; XOR swizzle keeps banks spread

typedef _Float16 f16x8 __attribute__((ext_vector_type(8)));
typedef float f32x4 __attribute__((ext_vector_type(4)));

// ---------------- K1: transpose (v,b,c,h,w) fp32 -> (v,b,h,w,c) fp16 --------
// Block 0 additionally computes proj matrices (threads 0..3) and the f16 MFMA
// B-fragment table Bfr[tap][lane] (threads 0..63): w[kd=lane&15][c=q*8+j][tap].
__global__ void k_transpose(const float* __restrict__ f, const float* __restrict__ pm,
                            const float* __restrict__ wt, ushort* __restrict__ featT,
                            float* __restrict__ P, ushort* __restrict__ Bfr) {
    __shared__ float t[Cc][Ww + 1];
    const int tid = threadIdx.x;
    if (blockIdx.x == 0 && tid < 64) {
        if (tid < Bb * (Vv - 1)) {
            int b = tid >> 1;
            int v = (tid & 1) + 1;
            const float* ref = pm + (b * Vv + 0) * 16;
            const float* src = pm + (b * Vv + v) * 16;
            float A[4][8];
            for (int i = 0; i < 4; ++i)
                for (int j = 0; j < 4; ++j) {
                    A[i][j] = ref[i * 4 + j];
                    A[i][4 + j] = (i == j) ? 1.0f : 0.0f;
                }
            for (int col = 0; col < 4; ++col) {
                int piv = col;
                for (int r = col + 1; r < 4; ++r)
                    if (fabsf(A[r][col]) > fabsf(A[piv][col])) piv = r;
                if (piv != col)
                    for (int j = 0; j < 8; ++j) { float tmp = A[col][j]; A[col][j] = A[piv][j]; A[piv][j] = tmp; }
                float inv = 1.0f / A[col][col];
                for (int j = 0; j < 8; ++j) A[col][j] *= inv;
                for (int r = 0; r < 4; ++r) {
                    if (r == col) continue;
                    float fct = A[r][col];
                    for (int j = 0; j < 8; ++j) A[r][j] -= fct * A[col][j];
                }
            }
            float Pm[3][4];
            for (int i = 0; i < 3; ++i)
                for (int j = 0; j < 4; ++j) {
                    float s = 0.f;
                    for (int k = 0; k < 4; ++k) s += src[i * 4 + k] * A[k][4 + j];
                    Pm[i][j] = s;
                }
            float* o = P + tid * 12;
            o[0] = Pm[0][0]; o[1] = Pm[0][1]; o[2] = Pm[0][2];
            o[3] = Pm[1][0]; o[4] = Pm[1][1]; o[5] = Pm[1][2];
            o[6] = Pm[2][0]; o[7] = Pm[2][1]; o[8] = Pm[2][2];
            o[9] = Pm[0][3]; o[10] = Pm[1][3]; o[11] = Pm[2][3];
        }
        int kd = tid & 15, q = tid >> 4;
        for (int tap = 0; tap < 9; ++tap) {
            ushort* dst = Bfr + (tap * 64 + tid) * 8;
            for (int j = 0; j < 8; ++j) {
                float w = (kd < 3) ? wt[(q * 8 + j) * 27 + kd * 9 + tap] : 0.f;
                __half h = __float2half(w);
                dst[j] = *(ushort*)&h;
            }
        }
    }
    int slice = blockIdx.x;          // vb*H + y
    int vb = slice / Hh, y = slice % Hh;
    const float* src = f + (size_t)vb * Cc * HW + (size_t)y * Ww;
    ushort* dst = featT + ((size_t)vb * Hh + y) * Ww * Cc;
    for (int i = tid; i < Cc * (Ww / 4); i += 256) {
        int c = i / (Ww / 4), x4 = (i - c * (Ww / 4)) * 4;
        float4 v = *(const float4*)(src + (size_t)c * HW + x4);
        t[c][x4] = v.x; t[c][x4 + 1] = v.y; t[c][x4 + 2] = v.z; t[c][x4 + 3] = v.w;
    }
    __syncthreads();
    for (int i = tid; i < Ww * 4; i += 256) {
        int x = i >> 2, c8 = i & 3;
        union { uint4 u; ushort s[8]; } pk;
#pragma unroll
        for (int j = 0; j < 8; ++j) {
            __half h = __float2half(t[c8 * 8 + j][x]);
            pk.s[j] = *(ushort*)&h;
        }
        *(uint4*)&dst[x * Cc + c8 * 8] = pk.u;
    }
}

// ---------------- K2: f16 variance tile + f16 MFMA 3x3 conv -> S (f16) ------
// R14 = R12 revert (best known: 149.55 us). Grid order (tile-fast, d, b) is
// deliberately kept: R13's XCD swizzle raised FETCH 5.7->30.7 MB and
// regressed — whole-d-row footprint (featT, 7.9 MB) caches fine as-is.
// k_main's ~76 us floor resisted: occupancy +25% (R9), VALU -20% (R10/R11),
// L1 layout 2x (R8 vs R11), L2 swizzle (R13). VALU-issue floor ~55 us;
// rest is barrier/gather-latency overlap.
__global__ __launch_bounds__(256, 5)
void k_main(const ushort* __restrict__ featT, const float* __restrict__ P,
            const float* __restrict__ dvals, const ushort* __restrict__ Bfr,
            ushort* __restrict__ S) {
    __shared__ ushort vsh[324 * VS];          // 20.7 KB f16 variance tile (32 ch)
    __shared__ unsigned int offs[324 * 4];    // 5.2 KB packed corner pixel idx
    __shared__ unsigned int wgts[324 * 4];    // 5.2 KB packed fp16 weights
    __shared__ float rt[24];
    const int tid = threadIdx.x;
    const int b = blockIdx.z, d = blockIdx.y;
    const int tileY = blockIdx.x / 10, tileX = blockIdx.x - (blockIdx.x / 10) * 10;

    if (tid < 24) rt[tid] = P[b * 24 + tid];
    const float depth = dvals[b * Dd + d];
    __syncthreads();

    // ---- stage A: bilinear coords for all 324 slots, once per block ----
#pragma unroll 1
    for (int p = tid; p < 324; p += 256) {
        int pyt = p / 18, pxt = p - pyt * 18;
        int gy = tileY * 16 + pyt - 1, gx = tileX * 16 + pxt - 1;
        if ((unsigned)gy >= (unsigned)Hh || (unsigned)gx >= (unsigned)Ww) continue;
#pragma unroll
        for (int vi = 0; vi < 2; ++vi) {
            const float* M = &rt[vi * 12];
            float fgx = (float)gx, fgy = (float)gy;
            float rx = M[0] * fgx + M[1] * fgy + M[2];
            float ry = M[3] * fgx + M[4] * fgy + M[5];
            float rz = M[6] * fgx + M[7] * fgy + M[8];
            float X = rx * depth + M[9];
            float Y = ry * depth + M[10];
            float Z = rz * depth + M[11];
            float z = (fabsf(Z) < 1e-6f) ? 1e-6f : Z;
            float u = X / z, vv = Y / z;
            float x0f = floorf(u), y0f = floorf(vv);
            float fx = u - x0f, fy = vv - y0f;
            int x0 = (int)x0f, y0 = (int)y0f;
            int x1 = x0 + 1, y1 = y0 + 1;
            bool vx0 = (x0 >= 0) && (x0 <= Ww - 1);
            bool vx1 = (x1 >= 0) && (x1 <= Ww - 1);
            bool vy0 = (y0 >= 0) && (y0 <= Hh - 1);
            bool vy1 = (y1 >= 0) && (y1 <= Hh - 1);
            int xc0 = min(max(x0, 0), Ww - 1), xc1 = min(max(x1, 0), Ww - 1);
            int yc0 = min(max(y0, 0), Hh - 1), yc1 = min(max(y1, 0), Hh - 1);
            unsigned int p00 = (unsigned)(yc0 * Ww + xc0);
            unsigned int p01 = (unsigned)(yc0 * Ww + xc1);
            unsigned int p10 = (unsigned)(yc1 * Ww + xc0);
            unsigned int p11 = (unsigned)(yc1 * Ww + xc1);
            float w0 = (vx0 && vy0) ? (1.f - fx) * (1.f - fy) : 0.f;
            float w1 = (vx1 && vy0) ? fx * (1.f - fy) : 0.f;
            float w2 = (vx0 && vy1) ? (1.f - fx) * fy : 0.f;
            float w3 = (vx1 && vy1) ? fx * fy : 0.f;
            offs[p * 4 + vi * 2 + 0] = p00 | (p01 << 16);
            offs[p * 4 + vi * 2 + 1] = p10 | (p11 << 16);
            __half2 ha = __floats2half2_rn(w0, w1);
            __half2 hb = __floats2half2_rn(w2, w3);
            wgts[p * 4 + vi * 2 + 0] = *(unsigned int*)&ha;
            wgts[p * 4 + vi * 2 + 1] = *(unsigned int*)&hb;
        }
    }
    __syncthreads();

    const ushort* b1 = featT + (size_t)(1 * Bb + b) * HW * Cc;
    const ushort* b2 = featT + (size_t)(2 * Bb + b) * HW * Cc;
    const ushort* br = featT + (size_t)b * HW * Cc;

    // ---- stage B: gather items (slot, c16 0..1): 648 items, f16 math ----
#pragma unroll 1
    for (int i = tid; i < 648; i += 256) {
        int p = i >> 1, half16 = i & 1;
        int c16 = half16 << 4;                 // channel offset 0 or 16
        int pyt = p / 18, pxt = p - pyt * 18;
        int gy = tileY * 16 + pyt - 1, gx = tileX * 16 + pxt - 1;
        int sw0 = ((half16 * 2 + 0) ^ (p & 3)) * 8;
        int sw1 = ((half16 * 2 + 1) ^ (p & 3)) * 8;
        ushort* dst0 = &vsh[p * VS + sw0];
        ushort* dst1 = &vsh[p * VS + sw1];
        if ((unsigned)gy >= (unsigned)Hh || (unsigned)gx >= (unsigned)Ww) {
            *(uint4*)dst0 = make_uint4(0u, 0u, 0u, 0u);
            *(uint4*)dst1 = make_uint4(0u, 0u, 0u, 0u);
            continue;
        }
        uint4 oo = *(const uint4*)&offs[p * 4];
        uint4 wwp = *(const uint4*)&wgts[p * 4];
        int o00 = (int)(oo.x & 0xffffu) * Cc + c16;
        int o01 = (int)(oo.x >> 16)     * Cc + c16;
        int o10 = (int)(oo.y & 0xffffu) * Cc + c16;
        int o11 = (int)(oo.y >> 16)     * Cc + c16;
        int o20 = (int)(oo.z & 0xffffu) * Cc + c16;
        int o21 = (int)(oo.z >> 16)     * Cc + c16;
        int o30 = (int)(oo.w & 0xffffu) * Cc + c16;
        int o31 = (int)(oo.w >> 16)     * Cc + c16;
        int orf = (gy * Ww + gx) * Cc + c16;
        __half2 hv0 = *(__half2*)&wwp.x;   // v0: (w0,w1)
        __half2 hv1 = *(__half2*)&wwp.y;   // v0: (w2,w3)
        __half2 hv2 = *(__half2*)&wwp.z;   // v1: (w0,w1)
        __half2 hv3 = *(__half2*)&wwp.w;   // v1: (w2,w3)
        __half2 w00 = __half2half2(__low2half(hv0)), w01 = __half2half2(__high2half(hv0));
        __half2 w02 = __half2half2(__low2half(hv1)), w03 = __half2half2(__high2half(hv1));
        __half2 w10 = __half2half2(__low2half(hv2)), w11 = __half2half2(__high2half(hv2));
        __half2 w12 = __half2half2(__low2half(hv3)), w13 = __half2half2(__high2half(hv3));
        const __half2 third2 = __float2half2_rn(1.0f / 3.0f);
        union U { uint4 u; __half2 h[4]; };
#pragma unroll
        for (int h = 0; h < 2; ++h) {
            int e = h * 8;
            U R, C0, C1, C2, C3, E0, E1, E2, E3, V;
            R.u  = *(const uint4*)(br + orf + e);
            C0.u = *(const uint4*)(b1 + o00 + e);
            C1.u = *(const uint4*)(b1 + o01 + e);
            C2.u = *(const uint4*)(b1 + o10 + e);
            C3.u = *(const uint4*)(b1 + o11 + e);
            E0.u = *(const uint4*)(b2 + o20 + e);
            E1.u = *(const uint4*)(b2 + o21 + e);
            E2.u = *(const uint4*)(b2 + o30 + e);
            E3.u = *(const uint4*)(b2 + o31 + e);
#pragma unroll
            for (int k = 0; k < 4; ++k) {
                __half2 s1 = __hmul2(w00, C0.h[k]);
                s1 = __hfma2(w01, C1.h[k], s1);
                s1 = __hfma2(w02, C2.h[k], s1);
                s1 = __hfma2(w03, C3.h[k], s1);
                __half2 s2 = __hmul2(w10, E0.h[k]);
                s2 = __hfma2(w11, E1.h[k], s2);
                s2 = __hfma2(w12, E2.h[k], s2);
                s2 = __hfma2(w13, E3.h[k], s2);
                __half2 r = R.h[k];
                __half2 sum = __hadd2(__hadd2(r, s1), s2);
                __half2 sq = __hmul2(r, r);
                sq = __hfma2(s1, s1, sq);
                sq = __hfma2(s2, s2, sq);
                __half2 m = __hmul2(sum, third2);
                __half2 var = __hfma2(__hneg2(m), m, __hmul2(sq, third2));
                V.h[k] = var;
            }
            *(uint4*)(h ? dst1 : dst0) = V.u;
        }
    }
    __syncthreads();

    // ---- phase 2: f16 MFMA conv. Wave covers 4 row-groups of 16 pixels. ----
    const int lane = tid & 63;
    const int wave = tid >> 6;
    const int q = lane >> 4;      // k-chunk selector (channels q*8..+7) / D row quad
    const int n = lane & 15;      // A: pixel-x ; B/D: kd column
    uint4 bf[9];
#pragma unroll
    for (int tap = 0; tap < 9; ++tap)
        bf[tap] = *(const uint4*)(Bfr + ((tap * 64 + lane) << 3));
#pragma unroll 1
    for (int rr = 0; rr < 4; ++rr) {
        int row = wave * 4 + rr;            // ty of this 16-pixel row-group
        f32x4 acc = {0.f, 0.f, 0.f, 0.f};
#pragma unroll
        for (int tap = 0; tap < 9; ++tap) {
            int kh = tap / 3, kw = tap - 3 * (tap / 3);
            int slot = (row + kh) * 18 + n + kw;
            union { uint4 u; f16x8 v; } A, Bf;
            A.u  = *(const uint4*)&vsh[slot * VS + (q ^ (slot & 3)) * 8];
            Bf.u = bf[tap];
            acc = __builtin_amdgcn_mfma_f32_16x16x32_f16(A.v, Bf.v, acc, 0, 0, 0);
        }
        if (n < 3) {   // lane holds D[pixel-x = q*4+reg][kd = n]; store 4 px as f16
            int gy = tileY * 16 + row;
            int gxb = tileX * 16 + q * 4;
            union { uint2 u; ushort s[4]; } pk;
#pragma unroll
            for (int j = 0; j < 4; ++j) {
                __half h = __float2half(acc[j]);
                pk.s[j] = *(ushort*)&h;
            }
            *(uint2*)&S[((size_t)(b * 3 + n) * Dd + d) * HW + (size_t)gy * Ww + gxb] = pk.u;
        }
    }
}

// ---------------- K3: cost, softmax, depth + conf; 2 px/thread, 4-way d ----
__global__ __launch_bounds__(256)
void k_post(const ushort* __restrict__ S, const float* __restrict__ dvals,
            float* __restrict__ out) {
    const int tid = threadIdx.x;
    const int lane = tid & 63, wave = tid >> 6;
    const int q = lane >> 4;                        // d-chunk: d = q*12 + j
    const int pl = lane & 15;                       // pixel-pair within group
    int gid = ((blockIdx.x * 4 + wave) * 16 + pl) * 2;   // global pixel (even)
    int b = gid / HW;
    int pix = gid - b * HW;
    const ushort* S0 = S + ((size_t)(b * 3 + 0) * Dd) * HW + pix;
    const ushort* S1 = S + ((size_t)(b * 3 + 1) * Dd) * HW + pix;
    const ushort* S2 = S + ((size_t)(b * 3 + 2) * Dd) * HW + pix;
    const int d0 = q * 12;
    float2 cost[12];
#pragma unroll
    for (int j = 0; j < 12; ++j) {
        int dd = d0 + j;
        float2 c = __half22float2(*(const __half2*)&S1[(size_t)dd * HW]);
        if (dd > 0) {
            float2 a = __half22float2(*(const __half2*)&S0[(size_t)(dd - 1) * HW]);
            c.x += a.x; c.y += a.y;
        }
        if (dd < Dd - 1) {
            float2 a = __half22float2(*(const __half2*)&S2[(size_t)(dd + 1) * HW]);
            c.x += a.x; c.y += a.y;
        }
        cost[j] = c;
    }
    float mx = cost[0].x, my = cost[0].y;
#pragma unroll
    for (int j = 1; j < 12; ++j) { mx = fmaxf(mx, cost[j].x); my = fmaxf(my, cost[j].y); }
    mx = fmaxf(mx, __shfl_xor(mx, 16)); mx = fmaxf(mx, __shfl_xor(mx, 32));
    my = fmaxf(my, __shfl_xor(my, 16)); my = fmaxf(my, __shfl_xor(my, 32));
    float sx = 0.f, sy = 0.f, depx = 0.f, depy = 0.f, dix = 0.f, diy = 0.f;
#pragma unroll
    for (int j = 0; j < 12; ++j) {
        float dv = dvals[b * Dd + d0 + j];
        float fd = (float)(d0 + j);
        float ex = __expf(cost[j].x - mx);
        float ey = __expf(cost[j].y - my);
        cost[j].x = ex; cost[j].y = ey;
        sx += ex; sy += ey;
        depx += ex * dv; depy += ey * dv;
        dix += ex * fd;  diy += ey * fd;
    }
    sx += __shfl_xor(sx, 16); sx += __shfl_xor(sx, 32);
    sy += __shfl_xor(sy, 16); sy += __shfl_xor(sy, 32);
    depx += __shfl_xor(depx, 16); depx += __shfl_xor(depx, 32);
    depy += __shfl_xor(depy, 16); depy += __shfl_xor(depy, 32);
    dix += __shfl_xor(dix, 16); dix += __shfl_xor(dix, 32);
    diy += __shfl_xor(diy, 16); diy += __shfl_xor(diy, 32);
    float invx = 1.0f / sx, invy = 1.0f / sy;
    int didx = min(max((int)(dix * invx), 0), Dd - 1);
    int didy = min(max((int)(diy * invy), 0), Dd - 1);
    float wx = 0.f, wy = 0.f;
#pragma unroll
    for (int j = 0; j < 12; ++j) {
        int dd = d0 + j;
        wx += ((dd >= didx - 1) && (dd <= didx + 2)) ? cost[j].x : 0.f;
        wy += ((dd >= didy - 1) && (dd <= didy + 2)) ? cost[j].y : 0.f;
    }
    wx += __shfl_xor(wx, 16); wx += __shfl_xor(wx, 32);
    wy += __shfl_xor(wy, 16); wy += __shfl_xor(wy, 32);
    if (q == 0) {
        *(float2*)&out[gid] = make_float2(depx * invx, depy * invy);
        *(float2*)&out[Bb * HW + gid] = make_float2(wx * invx, wy * invy);
    }
}

// ---------------- launch ----------------------------------------------------
extern "C" void kernel_launch(void* const* d_in, const int* in_sizes, int n_in,
                              void* d_out, int out_size, void* d_ws, size_t ws_size,
                              hipStream_t stream) {
    const float* features = (const float*)d_in[0];   // (V,B,C,H,W)
    const float* pm       = (const float*)d_in[1];   // (B,V,4,4)
    const float* dvals    = (const float*)d_in[2];   // (B,D)
    const float* reg_w    = (const float*)d_in[4];   // (1,C,3,3,3)
    float* outp = (float*)d_out;

    char* ws = (char*)d_ws;
    ushort* featT = (ushort*)ws;                                 // V*B*H*W*C f16
    size_t featT_bytes = (size_t)Vv * Bb * Hh * Ww * Cc * sizeof(ushort);
    float* P = (float*)(ws + featT_bytes);                       // 48 floats
    ushort* S = (ushort*)(ws + featT_bytes + 512);               // B*3*D*H*W f16
    size_t S_bytes = (size_t)Bb * 3 * Dd * HW * sizeof(ushort);
    ushort* Bfr = (ushort*)(ws + featT_bytes + 512 + S_bytes);   // 9*64*8 f16

    k_transpose<<<Vv * Bb * Hh, 256, 0, stream>>>(features, pm, reg_w, featT, P, Bfr);
    k_main<<<dim3(80, Dd, Bb), 256, 0, stream>>>(featT, P, dvals, Bfr, S);
    k_post<<<(Bb * HW) / 128, 256, 0, stream>>>(S, dvals, outp);
}